// Round 9
// baseline (519.973 us; speedup 1.0000x reference)
//
#include <hip/hip_runtime.h>
#include <math.h>

constexpr int Hn = 18, Wn = 18, HWn = 324;
constexpr int WPB = HWn / 4;        // 81 waves per b-row (4 tiles/wave)
constexpr int TICK_STRIDE = 16;     // one counter per 64B line

// Four tiles per wave; 16-lane group g owns tile wave*4+g.
// Column layout: lane l owns column x=l via slots j=0..17 (element j*18+l),
// plus tails x in {16,17}: slot 18+s -> (y=8s+(l>>1), x=16+(l&1)); slot 20
// valid only for l<4.  d^2 walks a 2-add recurrence (re-walked in pass C).
// Fused normalization: tick[] is zeroed by hipMemsetAsync each launch;
// each wave (all 4 tiles share one b) does release-fence + device atomicAdd;
// the 81st arriver re-reads the b-row with agent-scope loads and normalizes.
__global__ __launch_bounds__(256, 6) void psrw_kernel(
    const float* __restrict__ cv, const int* __restrict__ peak,
    float* __restrict__ out, unsigned* __restrict__ tick, int BC)
{
    int gtid = blockIdx.x * 256 + threadIdx.x;
    int wave = gtid >> 6;
    int lane = threadIdx.x & 63;
    int g = lane >> 4;
    int l = lane & 15;
    int tile = wave * 4 + g;
    if (tile >= BC) return;

    const float* row = cv + (size_t)tile * HWn;
    int2 pk = ((const int2*)peak)[tile];
    int py = pk.x & 31, px = pk.y & 31;   // range-pin: enables mul24

    const float* colp = row + l;
    float c[21];
#pragma unroll
    for (int j = 0; j < 18; ++j) c[j] = colp[18 * j];   // imm-offset loads
    int lh = l >> 1, lb = l & 1;
    const float* tp = row + (lh * 18 + 16 + lb);
    c[18] = tp[0];
    c[19] = tp[144];
    bool v20 = (l < 4);
    c[20] = v20 ? tp[288] : 0.f;          // flat idx <= 323: always in-tile

    float cpk = row[py * Wn + px];        // peak value (uniform per group)

    // ---- Pass A: max + total sum; rect sum gathered by lanes 0..8 ----
    float m0 = -INFINITY, m1 = -INFINITY, s0 = 0.f, s1 = 0.f;
#pragma unroll
    for (int j = 0; j < 18; j += 2) { m0 = fmaxf(m0, c[j]); s0 += c[j]; }
#pragma unroll
    for (int j = 1; j < 18; j += 2) { m1 = fmaxf(m1, c[j]); s1 += c[j]; }
    m0 = fmaxf(m0, c[18]); s0 += c[18];
    m1 = fmaxf(m1, c[19]); s1 += c[19];
    m0 = fmaxf(m0, v20 ? c[20] : -INFINITY); s0 += c[20];
    float m = fmaxf(m0, m1);
    float s = s0 + s1;

    int ry0 = max(0, py - 1), ry1 = min(Hn - 1, py + 1);
    int rx0 = max(0, px - 1), rx1 = min(Wn - 1, px + 1);
    float rectc = 0.f;
    if (l < 9) {
        int q = (l * 11) >> 5;            // l/3 for l<=8
        int r = l - 3 * q;
        int ry = ry0 + q, rx = rx0 + r;
        if (ry <= ry1 && rx <= rx1) rectc = row[ry * Wn + rx];  // L1 hit
    }
    s -= rectc;                           // fold rect removal into reduction
#pragma unroll
    for (int o = 8; o; o >>= 1) {
        s += __shfl_xor(s, o, 64);
        m = fmaxf(m, __shfl_xor(m, o, 64));
    }
    int n_pri = HWn - (ry1 - ry0 + 1) * (rx1 - rx0 + 1);
    float mean_pri = s / (float)n_pri;    // IEEE: feeds the keep-compare cliff

    // ---- Pass B: dminb = min over {c<=mean_pri} of (d2-1), unsigned ----
    // ddm1 = dy^2 + (dx^2-1); peak (d2=0) wraps to 0xFFFFFFFF -> auto-excluded.
    int dxl = l - px;
    int dx2m1 = dxl * dxl - 1;
    unsigned A = (unsigned)(py * py + dx2m1);  // dy = -py at j=0
    int Bs = 1 - 2 * py;                       // A += 2*dy+1 per j
    unsigned dminb = 0xFFFFFFFFu;
#pragma unroll
    for (int j = 0; j < 18; ++j) {
        unsigned t = min(dminb, A);
        dminb = (c[j] <= mean_pri) ? t : dminb;
        A += (unsigned)Bs; Bs += 2;
    }
    int dyt = lh - py;
    int dxt = 16 + lb - px;
    int dxt2m1 = dxt * dxt - 1;
#pragma unroll
    for (int s2 = 0; s2 < 3; ++s2) {
        int dy = dyt + 8 * s2;
        unsigned dd = (unsigned)(dy * dy + dxt2m1);
        if (s2 == 2 && !v20) dd = 0x7FFFFFFFu;   // invalid slot: far, not in-disk
        unsigned t = min(dminb, dd);
        dminb = (c[18 + s2] <= mean_pri) ? t : dminb;
    }
#pragma unroll
    for (int o = 8; o; o >>= 1)
        dminb = min(dminb, (unsigned)__shfl_xor((int)dminb, o, 64));

    // width = sqrt(dmin) (sentinel 100); disk test d2 <= clip(dmin,2,20) exact
    float width = (dminb > 577u) ? 100.f
                                 : __builtin_amdgcn_sqrtf((float)(dminb + 1u));
    unsigned rad2m1 = min(max(dminb, 1u), 19u);

    // ---- Pass C: survivors (d2-1 > rad2m1): sum, sumsq, in-disk count ----
    float sd0 = 0.f, sd1 = 0.f, ssd = 0.f;
    int cnt = 0;
    unsigned A2 = (unsigned)(py * py + dx2m1);
    int Bs2 = 1 - 2 * py;
#pragma unroll
    for (int j = 0; j < 18; ++j) {
        bool in = (A2 <= rad2m1);         // peak: 0xFFFFFFFF -> "survivor" (fixed below)
        float cm = in ? 0.f : c[j];
        if (j & 1) sd1 += cm; else sd0 += cm;
        ssd = fmaf(cm, cm, ssd);
        cnt += in ? 1 : 0;
        A2 += (unsigned)Bs2; Bs2 += 2;
    }
#pragma unroll
    for (int s2 = 0; s2 < 3; ++s2) {
        int dy = dyt + 8 * s2;
        unsigned dd = (unsigned)(dy * dy + dxt2m1);
        if (s2 == 2 && !v20) dd = 0x7FFFFFFFu;
        bool in = (dd <= rad2m1);
        float cm = in ? 0.f : c[18 + s2];
        if (s2 & 1) sd1 += cm; else sd0 += cm;
        ssd = fmaf(cm, cm, ssd);
        cnt += in ? 1 : 0;
    }
    float sd = sd0 + sd1;
#pragma unroll
    for (int o = 8; o; o >>= 1) {
        sd  += __shfl_xor(sd, o, 64);
        ssd += __shfl_xor(ssd, o, 64);
        cnt += __shfl_xor(cnt, o, 64);
    }
    // peak correction: it is always in-disk (d2=0 <= rad2 since rad2>=2)
    sd -= cpk;
    ssd = fmaf(-cpk, cpk, ssd);
    float n = (float)(HWn - 1 - cnt);
    float mean_s = sd * __builtin_amdgcn_rcpf(n);
    float var_s = fmaf(-sd, mean_s, ssd) * __builtin_amdgcn_rcpf(n - 1.f);
    float psrw = (m - mean_s) * __builtin_amdgcn_rcpf(fmaf(var_s, width, 1e-16f));
    if (l == 0) out[tile] = psrw;

    // ---- Fused normalization: 81st arriver of each b normalizes the row ----
    int b = wave / WPB;                   // all 4 tiles of a wave share b
    __threadfence();                      // release: psrw stores -> device
    unsigned tk = 0;
    if (lane == 0) tk = atomicAdd(&tick[b * TICK_STRIDE], 1u);  // device-scope
    tk = (unsigned)__shfl((int)tk, 0, 64);
    if (tk == (unsigned)(WPB - 1)) {      // exactly one wave per b (tick zeroed)
        float* rowo = out + (size_t)b * HWn;
        float vals[6];
        float sn = 0.f;
#pragma unroll
        for (int k = 0; k < 6; ++k) {
            int idx = lane + 64 * k;
            float v = 0.f;
            if (idx < HWn)
                v = __uint_as_float(__hip_atomic_load(
                        (const unsigned*)&rowo[idx],
                        __ATOMIC_RELAXED, __HIP_MEMORY_SCOPE_AGENT));
            vals[k] = v;
            sn += v;
        }
#pragma unroll
        for (int o = 32; o; o >>= 1) sn += __shfl_xor(sn, o, 64);
        float idv = 1.f / (sn / 324.f + 1e-8f);
#pragma unroll
        for (int k = 0; k < 6; ++k) {
            int idx = lane + 64 * k;
            if (idx < HWn) rowo[idx] = vals[k] * idv;
        }
    }
}

extern "C" void kernel_launch(void* const* d_in, const int* in_sizes, int n_in,
                              void* d_out, int out_size, void* d_ws, size_t ws_size,
                              hipStream_t stream) {
    const float* cv  = (const float*)d_in[0];
    const int* peak  = (const int*)d_in[1];
    // d_in[2]/d_in[3] (mesh_y/mesh_x) are broadcast index grids — recomputed.
    float* out = (float*)d_out;
    unsigned* tick = (unsigned*)d_ws;

    int BC = in_sizes[1] / 2;               // 82944 tiles
    int B = out_size / HWn;                 // 256 b-rows
    // Zero the ticket array every launch (graph-capture-legal, ~64KB).
    hipMemsetAsync(tick, 0, (size_t)B * TICK_STRIDE * sizeof(unsigned), stream);

    int waves = (BC + 3) / 4;               // 4 tiles per wave; 81 waves per b
    int blocks = (waves + 3) / 4;           // 4 waves per 256-thread block
    psrw_kernel<<<blocks, 256, 0, stream>>>(cv, peak, out, tick, BC);
}

// Round 10
// 25.195 us; speedup vs baseline: 20.6377x; 20.6377x over previous
//
#include <hip/hip_runtime.h>
#include <math.h>

constexpr int Hn = 18, Wn = 18, HWn = 324;

// DPP row_ror rotate within each aligned 16-lane group: pure-VALU cross-lane
// (no ds_bpermute, no lgkmcnt wait). All lanes are always active here.
template<int N>
__device__ __forceinline__ float ror16_f(float x) {
    return __int_as_float(__builtin_amdgcn_mov_dpp(
        __float_as_int(x), 0x120 | N, 0xF, 0xF, true));
}
template<int N>
__device__ __forceinline__ unsigned ror16_u(unsigned x) {
    return (unsigned)__builtin_amdgcn_mov_dpp(
        (int)x, 0x120 | N, 0xF, 0xF, true);
}
template<int N>
__device__ __forceinline__ int ror16_i(int x) {
    return __builtin_amdgcn_mov_dpp(x, 0x120 | N, 0xF, 0xF, true);
}

// Four tiles per wave; 16-lane group g owns tile wave*4+g.
// Column layout: lane l owns column x=l via slots j=0..17 (element j*18+l),
// plus tails x in {16,17}: slot 18+s -> (y=8s+(l>>1), x=16+(l&1)); slot 20
// valid only for l<4.  d^2 walks a 2-add recurrence (re-walked in pass C).
// All group reductions are DPP rotate-reductions (VALU-latency, not LDS).
__global__ __launch_bounds__(256, 6) void psrw_kernel(
    const float* __restrict__ cv, const int* __restrict__ peak,
    float* __restrict__ out, int BC)
{
    int gtid = blockIdx.x * 256 + threadIdx.x;
    int wave = gtid >> 6;
    int lane = threadIdx.x & 63;
    int g = lane >> 4;
    int l = lane & 15;
    int tile = wave * 4 + g;
    if (tile >= BC) return;

    const float* row = cv + (size_t)tile * HWn;
    int2 pk = ((const int2*)peak)[tile];
    int py = pk.x & 31, px = pk.y & 31;   // range-pin: enables mul24

    const float* colp = row + l;
    float c[21];
#pragma unroll
    for (int j = 0; j < 18; ++j) c[j] = colp[18 * j];   // imm-offset loads
    int lh = l >> 1, lb = l & 1;
    const float* tp = row + (lh * 18 + 16 + lb);
    c[18] = tp[0];
    c[19] = tp[144];
    bool v20 = (l < 4);
    c[20] = v20 ? tp[288] : 0.f;          // flat idx <= 323: always in-tile

    float cpk = row[py * Wn + px];        // peak value (uniform per group)

    // ---- Pass A: max + total sum; rect sum gathered by lanes 0..8 ----
    float m0 = -INFINITY, m1 = -INFINITY, s0 = 0.f, s1 = 0.f;
#pragma unroll
    for (int j = 0; j < 18; j += 2) { m0 = fmaxf(m0, c[j]); s0 += c[j]; }
#pragma unroll
    for (int j = 1; j < 18; j += 2) { m1 = fmaxf(m1, c[j]); s1 += c[j]; }
    m0 = fmaxf(m0, c[18]); s0 += c[18];
    m1 = fmaxf(m1, c[19]); s1 += c[19];
    m0 = fmaxf(m0, v20 ? c[20] : -INFINITY); s0 += c[20];
    float m = fmaxf(m0, m1);
    float s = s0 + s1;

    int ry0 = max(0, py - 1), ry1 = min(Hn - 1, py + 1);
    int rx0 = max(0, px - 1), rx1 = min(Wn - 1, px + 1);
    float rectc = 0.f;
    if (l < 9) {
        int q = (l * 11) >> 5;            // l/3 for l<=8
        int r = l - 3 * q;
        int ry = ry0 + q, rx = rx0 + r;
        if (ry <= ry1 && rx <= rx1) rectc = row[ry * Wn + rx];  // L1 hit
    }
    s -= rectc;                           // fold rect removal into reduction
    s += ror16_f<8>(s);  m = fmaxf(m, ror16_f<8>(m));
    s += ror16_f<4>(s);  m = fmaxf(m, ror16_f<4>(m));
    s += ror16_f<2>(s);  m = fmaxf(m, ror16_f<2>(m));
    s += ror16_f<1>(s);  m = fmaxf(m, ror16_f<1>(m));
    int n_pri = HWn - (ry1 - ry0 + 1) * (rx1 - rx0 + 1);
    float mean_pri = s / (float)n_pri;    // IEEE: feeds the keep-compare cliff

    // ---- Pass B: dminb = min over {c<=mean_pri} of (d2-1), unsigned ----
    // ddm1 = dy^2 + (dx^2-1); peak (d2=0) wraps to 0xFFFFFFFF -> auto-excluded.
    int dxl = l - px;
    int dx2m1 = dxl * dxl - 1;
    unsigned A = (unsigned)(py * py + dx2m1);  // dy = -py at j=0
    int Bs = 1 - 2 * py;                       // A += 2*dy+1 per j
    unsigned dminb = 0xFFFFFFFFu;
#pragma unroll
    for (int j = 0; j < 18; ++j) {
        unsigned t = min(dminb, A);
        dminb = (c[j] <= mean_pri) ? t : dminb;
        A += (unsigned)Bs; Bs += 2;
    }
    int dyt = lh - py;
    int dxt = 16 + lb - px;
    int dxt2m1 = dxt * dxt - 1;
#pragma unroll
    for (int s2 = 0; s2 < 3; ++s2) {
        int dy = dyt + 8 * s2;
        unsigned dd = (unsigned)(dy * dy + dxt2m1);
        if (s2 == 2 && !v20) dd = 0x7FFFFFFFu;   // invalid slot: far, not in-disk
        unsigned t = min(dminb, dd);
        dminb = (c[18 + s2] <= mean_pri) ? t : dminb;
    }
    dminb = min(dminb, ror16_u<8>(dminb));
    dminb = min(dminb, ror16_u<4>(dminb));
    dminb = min(dminb, ror16_u<2>(dminb));
    dminb = min(dminb, ror16_u<1>(dminb));

    // width = sqrt(dmin) (sentinel 100); disk test d2 <= clip(dmin,2,20) exact
    float width = (dminb > 577u) ? 100.f
                                 : __builtin_amdgcn_sqrtf((float)(dminb + 1u));
    unsigned rad2m1 = min(max(dminb, 1u), 19u);

    // ---- Pass C: survivors (d2-1 > rad2m1): sum, sumsq, in-disk count ----
    float sd0 = 0.f, sd1 = 0.f, ssd = 0.f;
    int cnt = 0;
    unsigned A2 = (unsigned)(py * py + dx2m1);
    int Bs2 = 1 - 2 * py;
#pragma unroll
    for (int j = 0; j < 18; ++j) {
        bool in = (A2 <= rad2m1);         // peak: 0xFFFFFFFF -> "survivor" (fixed below)
        float cm = in ? 0.f : c[j];
        if (j & 1) sd1 += cm; else sd0 += cm;
        ssd = fmaf(cm, cm, ssd);
        cnt += in ? 1 : 0;
        A2 += (unsigned)Bs2; Bs2 += 2;
    }
#pragma unroll
    for (int s2 = 0; s2 < 3; ++s2) {
        int dy = dyt + 8 * s2;
        unsigned dd = (unsigned)(dy * dy + dxt2m1);
        if (s2 == 2 && !v20) dd = 0x7FFFFFFFu;
        bool in = (dd <= rad2m1);
        float cm = in ? 0.f : c[18 + s2];
        if (s2 & 1) sd1 += cm; else sd0 += cm;
        ssd = fmaf(cm, cm, ssd);
        cnt += in ? 1 : 0;
    }
    float sd = sd0 + sd1;
    sd += ror16_f<8>(sd);  ssd += ror16_f<8>(ssd);  cnt += ror16_i<8>(cnt);
    sd += ror16_f<4>(sd);  ssd += ror16_f<4>(ssd);  cnt += ror16_i<4>(cnt);
    sd += ror16_f<2>(sd);  ssd += ror16_f<2>(ssd);  cnt += ror16_i<2>(cnt);
    sd += ror16_f<1>(sd);  ssd += ror16_f<1>(ssd);  cnt += ror16_i<1>(cnt);
    // peak correction: it is always in-disk (d2=0 <= rad2 since rad2>=2)
    sd -= cpk;
    ssd = fmaf(-cpk, cpk, ssd);
    float n = (float)(HWn - 1 - cnt);
    float mean_s = sd * __builtin_amdgcn_rcpf(n);
    float var_s = fmaf(-sd, mean_s, ssd) * __builtin_amdgcn_rcpf(n - 1.f);
    float psrw = (m - mean_s) * __builtin_amdgcn_rcpf(fmaf(var_s, width, 1e-16f));
    if (l == 0) out[tile] = psrw;
}

// Normalize each b-row of C=324 psrw values by (mean + 1e-8), in place.
__global__ __launch_bounds__(256) void norm_kernel(float* __restrict__ out, int B)
{
    int gtid = blockIdx.x * 256 + threadIdx.x;
    int wave = gtid >> 6;
    int lane = threadIdx.x & 63;
    if (wave >= B) return;
    float* row = out + (size_t)wave * HWn;
    float4 v0 = reinterpret_cast<float4*>(row)[lane];
    bool has2 = lane < 17;
    float4 v1 = make_float4(0.f, 0.f, 0.f, 0.f);
    if (has2) v1 = reinterpret_cast<float4*>(row)[64 + lane];
    float s = (v0.x + v0.y) + (v0.z + v0.w) + ((v1.x + v1.y) + (v1.z + v1.w));
#pragma unroll
    for (int o = 32; o; o >>= 1) s += __shfl_xor(s, o, 64);
    float denom = s / 324.0f + 1e-8f;
    v0.x /= denom; v0.y /= denom; v0.z /= denom; v0.w /= denom;
    reinterpret_cast<float4*>(row)[lane] = v0;
    if (has2) {
        v1.x /= denom; v1.y /= denom; v1.z /= denom; v1.w /= denom;
        reinterpret_cast<float4*>(row)[64 + lane] = v1;
    }
}

extern "C" void kernel_launch(void* const* d_in, const int* in_sizes, int n_in,
                              void* d_out, int out_size, void* d_ws, size_t ws_size,
                              hipStream_t stream) {
    const float* cv  = (const float*)d_in[0];
    const int* peak  = (const int*)d_in[1];
    // d_in[2]/d_in[3] (mesh_y/mesh_x) are broadcast index grids — recomputed.
    float* out = (float*)d_out;

    int BC = in_sizes[1] / 2;               // 82944 tiles
    int waves = (BC + 3) / 4;               // 4 tiles per wave
    int blocks1 = (waves + 3) / 4;          // 4 waves per 256-thread block
    psrw_kernel<<<blocks1, 256, 0, stream>>>(cv, peak, out, BC);

    int B = out_size / HWn;
    int blocks2 = (B + 3) / 4;
    norm_kernel<<<blocks2, 256, 0, stream>>>(out, B);
}